// Round 16
// baseline (140.017 us; speedup 1.0000x reference)
//
#include <hip/hip_runtime.h>
#include <hip/hip_bf16.h>

// ---------------------------------------------------------------------------
// TrXL block on MI355X. bf16 MFMA everywhere, fp32 residual spine.
//   h1, Q, K, attn_out, h2 : bf16 [B*S=8192, 512]
//   Vt                     : bf16 [B, H, dh=64, S=2048]
//   h_ln_post              : fp32 [8192, 512]
//   weights prepped to Bt  : bf16 [N][K=512]  (QKV stacked to N=1536)
// attn14_k (R16 = R15 + token-offset fix): T15 score-pipelined attn12.
//   K staged 2-ahead (KA/KB), V 1-ahead (VA/VB); per iter: QK(t+1) MFMA
//   adjacent to exp/pack(t) VALU (independent -> co-issue), then PV(t).
//   STAGE_* takes TOKEN offsets — call sites pass tile*64 (R15 bug fixed).
// GEMMs: m97 double-buffered glds16 pipeline. prep_ln_k merges prep+LN1.
// ---------------------------------------------------------------------------

typedef __attribute__((ext_vector_type(8))) short bf16x8;
typedef __attribute__((ext_vector_type(4))) float f32x4;
typedef __attribute__((ext_vector_type(16))) float f32x16;
typedef __attribute__((ext_vector_type(8))) unsigned short u16x8;

typedef union { bf16x8 v; unsigned u[4]; u16x8 s; } frag_u;

typedef const unsigned int __attribute__((address_space(1)))* gas_t;
typedef unsigned int __attribute__((address_space(3)))* las_t;
static __device__ __forceinline__ void glds16(const void* g, void* l) {
    __builtin_amdgcn_global_load_lds((gas_t)g, (las_t)l, 16, 0, 0);
}

static __device__ __forceinline__ unsigned short f2b(float f) {
    union { float f; unsigned u; } a; a.f = f;
    unsigned r = a.u + 0x7FFFu + ((a.u >> 16) & 1u);   // RNE
    return (unsigned short)(r >> 16);
}
static __device__ __forceinline__ float b2f(unsigned short u) {
    union { unsigned u; float f; } c; c.u = ((unsigned)u) << 16; return c.f;
}
static __device__ __forceinline__ unsigned pack_bf16(float lo, float hi) {
    __hip_bfloat162 p = __float22bfloat162_rn(make_float2(lo, hi));
    unsigned r; __builtin_memcpy(&r, &p, 4); return r;
}
static __device__ __forceinline__ float fexp2(float x) {
#if __has_builtin(__builtin_amdgcn_exp2f)
    return __builtin_amdgcn_exp2f(x);     // bare v_exp_f32; scores bounded
#else
    return exp2f(x);
#endif
}
static __device__ __forceinline__ void swap32(int hi, unsigned a, unsigned b,
                                              unsigned& x, unsigned& y) {
#if __has_builtin(__builtin_amdgcn_permlane32_swap)
    typedef __attribute__((ext_vector_type(2))) int i32x2;
    i32x2 r = __builtin_amdgcn_permlane32_swap((int)a, (int)b, false, false);
    x = (unsigned)r[0]; y = (unsigned)r[1];
#else
    unsigned ta = (unsigned)__shfl_xor((int)a, 32);
    unsigned tb = (unsigned)__shfl_xor((int)b, 32);
    x = hi ? tb : a;
    y = hi ? b : ta;
#endif
}

// ---- LayerNorm row helper (one wave per 512-row) ---------------------------
static __device__ __forceinline__ void ln_row(
    const float* __restrict__ X, const float* __restrict__ gam,
    const float* __restrict__ bet, unsigned short* __restrict__ O,
    int row, int lane)
{
    const float4* xr = (const float4*)(X + (size_t)row * 512);
    float4 v0 = xr[lane * 2], v1 = xr[lane * 2 + 1];
    float vv[8] = {v0.x, v0.y, v0.z, v0.w, v1.x, v1.y, v1.z, v1.w};
    float s = 0.f, s2 = 0.f;
    #pragma unroll
    for (int j = 0; j < 8; ++j) { s += vv[j]; s2 += vv[j] * vv[j]; }
    #pragma unroll
    for (int d = 1; d < 64; d <<= 1) { s += __shfl_xor(s, d); s2 += __shfl_xor(s2, d); }
    float mean = s * (1.0f / 512.0f);
    float var  = s2 * (1.0f / 512.0f) - mean * mean;
    float rstd = rsqrtf(var + 1e-5f);
    int c = lane * 8;
    u16x8 o;
    #pragma unroll
    for (int j = 0; j < 8; ++j) o[j] = f2b((vv[j] - mean) * rstd * gam[c + j] + bet[c + j]);
    *(u16x8*)(O + (size_t)row * 512 + c) = o;
}

// ---- merged: weight prep (blocks 0..1023) + LN1 (blocks 1024..3071) -------
__global__ __launch_bounds__(256) void prep_ln_k(
    const float* __restrict__ Wq, const float* __restrict__ Wk, const float* __restrict__ Wv,
    const float* __restrict__ Wm, const float* __restrict__ Wo,
    unsigned short* __restrict__ wqT, unsigned short* __restrict__ wkT,
    unsigned short* __restrict__ wvT, unsigned short* __restrict__ wmT,
    unsigned short* __restrict__ woT,
    const float* __restrict__ X, const float* __restrict__ g1,
    const float* __restrict__ b1, unsigned short* __restrict__ h1)
{
    int bx = blockIdx.x;
    if (bx < 1024) {
        int idx = bx * 256 + threadIdx.x;     // idx = n*512 + k
        int n = idx >> 9, k = idx & 511;
        int h = n >> 6, e = n & 63;
        size_t src_qkv = ((size_t)h * 512 + k) * 64 + e;
        wqT[idx] = f2b(Wq[src_qkv]);
        wkT[idx] = f2b(Wk[src_qkv]);
        wvT[idx] = f2b(Wv[src_qkv]);
        wmT[idx] = f2b(Wm[(size_t)k * 512 + n]);
        woT[idx] = f2b(Wo[(size_t)k * 512 + n]);
    } else {
        int row = (bx - 1024) * 4 + (threadIdx.x >> 6);
        ln_row(X, g1, b1, h1, row, threadIdx.x & 63);
    }
}

// ---- LN, 4 rows per 256-thread block --------------------------------------
__global__ __launch_bounds__(256) void ln4_k(
    const float* __restrict__ X, const float* __restrict__ gam,
    const float* __restrict__ bet, unsigned short* __restrict__ O)
{
    int row = blockIdx.x * 4 + (threadIdx.x >> 6);
    ln_row(X, gam, bet, O, row, threadIdx.x & 63);
}

// ---- fused QKV GEMM: [8192,512] x Bt[1536,512]^T, DBUF glds16 pipeline ----
__global__ __launch_bounds__(256) void gemm_qkv_k(
    const unsigned short* __restrict__ A, const unsigned short* __restrict__ Bt,
    const float* __restrict__ bq, const float* __restrict__ bk, const float* __restrict__ bv,
    unsigned short* __restrict__ Qo, unsigned short* __restrict__ Ko,
    unsigned short* __restrict__ VtO)
{
    __shared__ unsigned short Al[2][128 * 32];   // linear [row][k], row = 64B
    __shared__ unsigned short Bl[2][128 * 32];
    int tid = threadIdx.x;
    int wid = tid >> 6, lane = tid & 63;
    int lr = lane & 15, lg = lane >> 4;
    int m0 = blockIdx.x * 128, n0 = blockIdx.y * 128;
    int seg = blockIdx.y >> 2;
    int wr = (wid >> 1) * 64, wc = (wid & 1) * 64;
    f32x4 acc[4][4] = {};
    const unsigned short* Ag = A  + (size_t)(m0 + wid * 32 + (lane >> 2)) * 512 + (lane & 3) * 8;
    const unsigned short* Bg = Bt + (size_t)(n0 + wid * 32 + (lane >> 2)) * 512 + (lane & 3) * 8;
    const int lofs = wid * 32 * 32;

    auto STAGE = [&](int buf, int k0) {
        glds16(Ag + k0,            Al[buf] + lofs);
        glds16(Ag + k0 + 16 * 512, Al[buf] + lofs + 16 * 32);
        glds16(Bg + k0,            Bl[buf] + lofs);
        glds16(Bg + k0 + 16 * 512, Bl[buf] + lofs + 16 * 32);
    };
    auto COMPUTE = [&](int buf) {
        bf16x8 af[4], bfr[4];
        #pragma unroll
        for (int m = 0; m < 4; ++m) af[m]  = *(const bf16x8*)(Al[buf] + (wr + m * 16 + lr) * 32 + lg * 8);
        #pragma unroll
        for (int n = 0; n < 4; ++n) bfr[n] = *(const bf16x8*)(Bl[buf] + (wc + n * 16 + lr) * 32 + lg * 8);
        #pragma unroll
        for (int m = 0; m < 4; ++m)
            #pragma unroll
            for (int n = 0; n < 4; ++n)
                acc[m][n] = __builtin_amdgcn_mfma_f32_16x16x32_bf16(af[m], bfr[n], acc[m][n], 0, 0, 0);
    };

    STAGE(0, 0);
    #pragma unroll 1
    for (int k0 = 0; k0 < 512; k0 += 64) {
        __syncthreads();
        if (k0 + 32 < 512) STAGE(1, k0 + 32);
        COMPUTE(0);
        __syncthreads();
        if (k0 + 64 < 512) STAGE(0, k0 + 64);
        COMPUTE(1);
    }

    const float* bb = seg == 0 ? bq : (seg == 1 ? bk : bv);
    unsigned short* dst = seg == 0 ? Qo : Ko;
    #pragma unroll
    for (int m = 0; m < 4; ++m)
      #pragma unroll
      for (int n = 0; n < 4; ++n) {
        int gr0 = m0 + wr + m * 16 + 4 * lg;
        int nc  = ((blockIdx.y & 3) << 7) + wc + n * 16 + lr;
        float bias = bb[nc];
        if (seg < 2) {
            #pragma unroll
            for (int j = 0; j < 4; ++j)
                dst[(size_t)(gr0 + j) * 512 + nc] = f2b(acc[m][n][j] + bias);
        } else {
            int bbk = gr0 >> 11, ss = gr0 & 2047, hh = nc >> 6, ee = nc & 63;
            ushort4 pv;
            pv.x = f2b(acc[m][n][0] + bias);
            pv.y = f2b(acc[m][n][1] + bias);
            pv.z = f2b(acc[m][n][2] + bias);
            pv.w = f2b(acc[m][n][3] + bias);
            *(ushort4*)&VtO[((size_t)((bbk * 8 + hh) * 64 + ee) << 11) + ss] = pv;
        }
      }
}

// ---- GEMM 128x64 tiles, DBUF glds16 pipeline, fp32 epilogue ---------------
template<int MODE>
__global__ __launch_bounds__(256) void gemm_n64_k(
    const unsigned short* __restrict__ A, const unsigned short* __restrict__ Bt,
    const float* __restrict__ bias, const float* __restrict__ aux,
    float* __restrict__ Cout)
{
    __shared__ unsigned short Al[2][128 * 32];
    __shared__ unsigned short Bl[2][64 * 32];
    int tid = threadIdx.x;
    int wid = tid >> 6, lane = tid & 63;
    int lr = lane & 15, lg = lane >> 4;
    int m0 = blockIdx.x * 128, n0 = blockIdx.y * 64;
    int wr = wid * 32;
    f32x4 acc[2][4] = {};
    const unsigned short* Ag = A  + (size_t)(m0 + wid * 32 + (lane >> 2)) * 512 + (lane & 3) * 8;
    const unsigned short* Bg = Bt + (size_t)(n0 + wid * 16 + (lane >> 2)) * 512 + (lane & 3) * 8;
    const int aofs = wid * 32 * 32;
    const int bofs = wid * 16 * 32;

    auto STAGE = [&](int buf, int k0) {
        glds16(Ag + k0,            Al[buf] + aofs);
        glds16(Ag + k0 + 16 * 512, Al[buf] + aofs + 16 * 32);
        glds16(Bg + k0,            Bl[buf] + bofs);
    };
    auto COMPUTE = [&](int buf) {
        bf16x8 af[2], bfr[4];
        #pragma unroll
        for (int m = 0; m < 2; ++m) af[m]  = *(const bf16x8*)(Al[buf] + (wr + m * 16 + lr) * 32 + lg * 8);
        #pragma unroll
        for (int n = 0; n < 4; ++n) bfr[n] = *(const bf16x8*)(Bl[buf] + (n * 16 + lr) * 32 + lg * 8);
        #pragma unroll
        for (int m = 0; m < 2; ++m)
            #pragma unroll
            for (int n = 0; n < 4; ++n)
                acc[m][n] = __builtin_amdgcn_mfma_f32_16x16x32_bf16(af[m], bfr[n], acc[m][n], 0, 0, 0);
    };

    STAGE(0, 0);
    #pragma unroll 1
    for (int k0 = 0; k0 < 512; k0 += 64) {
        __syncthreads();
        if (k0 + 32 < 512) STAGE(1, k0 + 32);
        COMPUTE(0);
        __syncthreads();
        if (k0 + 64 < 512) STAGE(0, k0 + 64);
        COMPUTE(1);
    }

    #pragma unroll
    for (int m = 0; m < 2; ++m)
      #pragma unroll
      for (int n = 0; n < 4; ++n)
        #pragma unroll
        for (int j = 0; j < 4; ++j) {
            int gr = m0 + wr + m * 16 + 4 * lg + j;
            int gc = n0 + n * 16 + lr;
            float v = acc[m][n][j] + bias[gc];
            if (MODE == 3) v = v > 0.0f ? v : 0.0f;
            Cout[(size_t)gr * 512 + gc] = v + aux[(size_t)gr * 512 + gc];
        }
}

// ---- attn14 (fixed): T15 score-pipelined attn12 ---------------------------
// Even tiles live in KA/VA, odd in KB/VB. Iter t: stage K(t+2), V(t+1);
// QK(t+1) [independent MFMA] + exp/pack(t) [VALU] + PV(t); barrier.
// STAGE_* takes TOKEN offsets (tile*64) — the R15 bug was passing tile idx.
__global__ __launch_bounds__(128) void attn14_k(
    const unsigned short* __restrict__ Q, const unsigned short* __restrict__ K,
    const unsigned short* __restrict__ Vt, unsigned short* __restrict__ O)
{
    __shared__ __align__(16) unsigned short KlA[4096], KlB[4096];   // 8 KB each
    __shared__ __align__(16) unsigned short VlA[4096], VlB[4096];

    const int tid  = threadIdx.x;
    const int lane = tid & 63;
    const int q31  = lane & 31;
    const int hi   = lane >> 5;
    const int wid  = tid >> 6;           // 0: K-stager, 1: V-stager

    // XCD swizzle: 32 q-blocks of one (b,h) share an XCD's L2
    int bid = blockIdx.x;
    int xcd = bid & 7, idx = bid >> 3;   // idx 0..127
    int bh  = xcd + 8 * (idx >> 5);      // 0..31
    int qt  = idx & 31;
    int b = bh >> 3, h = bh & 7;
    int q0 = qt * 64 + wid * 32;

    const unsigned short* Qb = Q  + (size_t)b * 2048 * 512 + h * 64;
    const unsigned short* Kb = K  + (size_t)b * 2048 * 512 + h * 64;
    const unsigned short* Vb = Vt + (size_t)(b * 8 + h) * 64 * 2048;

    // Q B-frags, pre-scaled by 1/sqrt(dh) * log2(e)
    frag_u qf[4];
    const float qs = 0.125f * 1.44269504f;
    #pragma unroll
    for (int ds = 0; ds < 4; ++ds) {
        u16x8 raw = *(const u16x8*)(Qb + (size_t)(q0 + q31) * 512 + ds * 16 + hi * 8);
        #pragma unroll
        for (int i = 0; i < 4; ++i)
            qf[ds].u[i] = pack_bf16(b2f(raw[2 * i]) * qs, b2f(raw[2 * i + 1]) * qs);
    }

    // all-ones B-frag for the l-accumulating MFMA
    frag_u onesf;
    #pragma unroll
    for (int i = 0; i < 4; ++i) onesf.u[i] = 0x3F803F80u;

    // inverse-swizzle per-lane source offsets (ushort elements), j = 0..7
    unsigned soff[8];
    #pragma unroll
    for (int j = 0; j < 8; ++j) {
        int row31 = j * 4 + (lane >> 4);
        int x = (lane & 15) ^ (row31 & 15);
        int t = 32 * (x >> 3) + row31;
        int s = x & 7;
        soff[j] = (wid == 0) ? (unsigned)(t * 512 + s * 8)     // K[t][s*8..]
                             : (unsigned)(t * 2048 + s * 8);   // Vt row e=t
    }

    auto STAGE_K = [&](unsigned short* buf, int tok0) {   // tok0 = token offset
        if (wid == 0) {
            const unsigned short* g = Kb + (size_t)tok0 * 512;
            #pragma unroll
            for (int j = 0; j < 8; ++j) glds16(g + soff[j], buf + j * 512);
        }
    };
    auto STAGE_V = [&](unsigned short* buf, int tok0) {
        if (wid == 1) {
            const unsigned short* g = Vb + tok0;
            #pragma unroll
            for (int j = 0; j < 8; ++j) glds16(g + soff[j], buf + j * 512);
        }
    };

    f32x16 acc0, acc1, lacc;
    #pragma unroll
    for (int r = 0; r < 16; ++r) { acc0[r] = 0.0f; acc1[r] = 0.0f; lacc[r] = 0.0f; }
    const int swz = (q31 & 15) << 4;

    // QK: scores of one tile from K buffer (no setprio — keep interleavable)
    auto QK = [&](const unsigned short* Kh_, f32x16& s0, f32x16& s1) {
        const char* Kh = (const char*)Kh_;
        #pragma unroll
        for (int r = 0; r < 16; ++r) { s0[r] = 0.0f; s1[r] = 0.0f; }
        #pragma unroll
        for (int ds = 0; ds < 4; ++ds) {
            bf16x8 k0 = *(const bf16x8*)(Kh + q31 * 256 + ((ds * 32 + hi * 16) ^ swz));
            bf16x8 k1 = *(const bf16x8*)(Kh + q31 * 256 + ((128 + ds * 32 + hi * 16) ^ swz));
            s0 = __builtin_amdgcn_mfma_f32_32x32x16_bf16(k0, qf[ds].v, s0, 0, 0, 0);
            s1 = __builtin_amdgcn_mfma_f32_32x32x16_bf16(k1, qf[ds].v, s1, 0, 0, 0);
        }
    };

    // exp + pack + PV + lacc for one tile's scores
    auto SMPV = [&](f32x16& s0, f32x16& s1, const unsigned short* Vh_) {
        const char* Vh = (const char*)Vh_;
        #pragma unroll
        for (int r = 0; r < 16; ++r) {
            s0[r] = fexp2(s0[r]);
            s1[r] = fexp2(s1[r]);
        }
        frag_u pa[4];
        #pragma unroll
        for (int g = 0; g < 2; ++g) {
            unsigned A0 = pack_bf16(s0[8 * g + 0], s0[8 * g + 1]);
            unsigned A1 = pack_bf16(s0[8 * g + 2], s0[8 * g + 3]);
            unsigned A2 = pack_bf16(s0[8 * g + 4], s0[8 * g + 5]);
            unsigned A3 = pack_bf16(s0[8 * g + 6], s0[8 * g + 7]);
            swap32(hi, A0, A2, pa[g].u[0], pa[g].u[2]);
            swap32(hi, A1, A3, pa[g].u[1], pa[g].u[3]);
            unsigned B0 = pack_bf16(s1[8 * g + 0], s1[8 * g + 1]);
            unsigned B1 = pack_bf16(s1[8 * g + 2], s1[8 * g + 3]);
            unsigned B2 = pack_bf16(s1[8 * g + 4], s1[8 * g + 5]);
            unsigned B3 = pack_bf16(s1[8 * g + 6], s1[8 * g + 7]);
            swap32(hi, B0, B2, pa[2 + g].u[0], pa[2 + g].u[2]);
            swap32(hi, B1, B3, pa[2 + g].u[1], pa[2 + g].u[3]);
        }
        __builtin_amdgcn_s_setprio(1);
        #pragma unroll
        for (int ks = 0; ks < 4; ++ks) {
            bf16x8 v0 = *(const bf16x8*)(Vh + q31 * 256 + ((ks * 32 + hi * 16) ^ swz));
            bf16x8 v1 = *(const bf16x8*)(Vh + q31 * 256 + ((128 + ks * 32 + hi * 16) ^ swz));
            acc0 = __builtin_amdgcn_mfma_f32_32x32x16_bf16(pa[ks].v, v0, acc0, 0, 0, 0);
            acc1 = __builtin_amdgcn_mfma_f32_32x32x16_bf16(pa[ks].v, v1, acc1, 0, 0, 0);
            lacc = __builtin_amdgcn_mfma_f32_32x32x16_bf16(pa[ks].v, onesf.v, lacc, 0, 0, 0);
        }
        __builtin_amdgcn_s_setprio(0);
    };

    f32x16 p0, p1, n0, n1;   // scores: p = even-phase tile, n = odd-phase tile

    // prologue: K0,V0 -> A bufs; barrier; K1 -> KB (in flight); scores0; barrier
    STAGE_K(KlA, 0);
    STAGE_V(VlA, 0);
    __syncthreads();                 // K0,V0 ready
    STAGE_K(KlB, 64);                // tile 1, in flight across scores0
    QK(KlA, p0, p1);                 // scores of tile 0
    __syncthreads();                 // K1 drained; all waves done reading K0

    #pragma unroll 1
    for (int t = 0; t < 32; t += 2) {
        // even phase: QK(t+1) from KB ; softmax+PV(t) from VA
        if (t + 2 < 32) STAGE_K(KlA, (t + 2) * 64);
        STAGE_V(VlB, (t + 1) * 64);
        QK(KlB, n0, n1);             // scores t+1 (indep of p softmax)
        SMPV(p0, p1, VlA);           // exp/pack(t) + PV(t)
        __syncthreads();
        // odd phase: QK(t+2) from KA ; softmax+PV(t+1) from VB
        if (t + 3 < 32) STAGE_K(KlB, (t + 3) * 64);
        if (t + 2 < 32) {
            STAGE_V(VlA, (t + 2) * 64);
            QK(KlA, p0, p1);         // scores t+2
        }
        SMPV(n0, n1, VlB);           // exp/pack(t+1) + PV(t+1)
        __syncthreads();
    }

    // epilogue: element-wise divide (lacc[r] holds rowsum for acc*'s row)
    #pragma unroll
    for (int r = 0; r < 16; ++r) {
        int cr = (r & 3) + 8 * (r >> 2) + 4 * hi;
        float li = 1.0f / lacc[r];
        size_t rowoff = (size_t)(b * 2048 + q0 + cr) * 512 + h * 64 + q31;
        O[rowoff]      = f2b(acc0[r] * li);
        O[rowoff + 32] = f2b(acc1[r] * li);
    }
}

// ---------------------------------------------------------------------------
extern "C" void kernel_launch(void* const* d_in, const int* in_sizes, int n_in,
                              void* d_out, int out_size, void* d_ws, size_t ws_size,
                              hipStream_t stream)
{
    const float* x  = (const float*)d_in[0];
    const float* g1 = (const float*)d_in[1];
    const float* b1 = (const float*)d_in[2];
    const float* Wq = (const float*)d_in[3];
    const float* bq = (const float*)d_in[4];
    const float* Wk = (const float*)d_in[5];
    const float* bk = (const float*)d_in[6];
    const float* Wv = (const float*)d_in[7];
    const float* bv = (const float*)d_in[8];
    const float* Wm = (const float*)d_in[9];
    const float* bm = (const float*)d_in[10];
    const float* g2 = (const float*)d_in[11];
    const float* b2 = (const float*)d_in[12];
    const float* Wo = (const float*)d_in[13];
    const float* bo = (const float*)d_in[14];
    float* out = (float*)d_out;

    char* ws = (char*)d_ws;
    const size_t EB = (size_t)8192 * 512 * 2;
    unsigned short* h1  = (unsigned short*)(ws);
    unsigned short* qb  = (unsigned short*)(ws + EB);
    unsigned short* kb  = (unsigned short*)(ws + 2 * EB);
    unsigned short* vtb = (unsigned short*)(ws + 3 * EB);
    unsigned short* ao  = (unsigned short*)(ws + 4 * EB);
    unsigned short* h2  = (unsigned short*)(ws + 5 * EB);
    float*          hlp = (float*)(ws + 6 * EB);
    unsigned short* wqT = (unsigned short*)(ws + 8 * EB);   // QKV stacked [1536][512]
    unsigned short* wkT = wqT + 512 * 512;
    unsigned short* wvT = wkT + 512 * 512;
    unsigned short* wmT = wvT + 512 * 512;
    unsigned short* woT = wmT + 512 * 512;

    prep_ln_k<<<3072, 256, 0, stream>>>(Wq, Wk, Wv, Wm, Wo,
                                        wqT, wkT, wvT, wmT, woT,
                                        x, g1, b1, h1);
    gemm_qkv_k<<<dim3(64, 12), 256, 0, stream>>>(h1, wqT, bq, bk, bv, qb, kb, vtb);
    attn14_k<<<1024, 128, 0, stream>>>(qb, kb, vtb, ao);
    gemm_n64_k<2><<<dim3(64, 8), 256, 0, stream>>>(ao, wmT, bm, x, hlp);
    ln4_k<<<2048, 256, 0, stream>>>(hlp, g2, b2, h2);
    gemm_n64_k<3><<<dim3(64, 8), 256, 0, stream>>>(h2, woT, bo, hlp, out);
}

// Round 17
// 130.485 us; speedup vs baseline: 1.0731x; 1.0731x over previous
//
#include <hip/hip_runtime.h>
#include <hip/hip_bf16.h>

// ---------------------------------------------------------------------------
// TrXL block on MI355X. bf16 MFMA everywhere, fp32 residual spine.
//   h1, Q, K, attn_out, h2 : bf16 [B*S=8192, 512]
//   Vt                     : bf16 [B, H, dh=64, S=2048]
//   h_ln_post              : fp32 [8192, 512]
//   weights prepped to Bt  : bf16 [N][K=512]  (QKV stacked to N=1536)
// attn12_k (champion): 2-wave, glds16 pre-swizzled staging, dbuf,
//   1 barrier/tile, max-free softmax, lacc via ones-MFMA.
// GEMMs: m97 double-buffered glds16 pipeline + T1 XCD swizzle on x
//   (per-XCD A-slice 1MB + Bt panel fit the 4MB per-XCD L2).
// prep_ln_k merges weight-prep + LN1; LNs 4 rows/block.
// ---------------------------------------------------------------------------

typedef __attribute__((ext_vector_type(8))) short bf16x8;
typedef __attribute__((ext_vector_type(4))) float f32x4;
typedef __attribute__((ext_vector_type(16))) float f32x16;
typedef __attribute__((ext_vector_type(8))) unsigned short u16x8;

typedef union { bf16x8 v; unsigned u[4]; u16x8 s; } frag_u;

typedef const unsigned int __attribute__((address_space(1)))* gas_t;
typedef unsigned int __attribute__((address_space(3)))* las_t;
static __device__ __forceinline__ void glds16(const void* g, void* l) {
    __builtin_amdgcn_global_load_lds((gas_t)g, (las_t)l, 16, 0, 0);
}

static __device__ __forceinline__ unsigned short f2b(float f) {
    union { float f; unsigned u; } a; a.f = f;
    unsigned r = a.u + 0x7FFFu + ((a.u >> 16) & 1u);   // RNE
    return (unsigned short)(r >> 16);
}
static __device__ __forceinline__ float b2f(unsigned short u) {
    union { unsigned u; float f; } c; c.u = ((unsigned)u) << 16; return c.f;
}
static __device__ __forceinline__ unsigned pack_bf16(float lo, float hi) {
    __hip_bfloat162 p = __float22bfloat162_rn(make_float2(lo, hi));
    unsigned r; __builtin_memcpy(&r, &p, 4); return r;
}
static __device__ __forceinline__ float fexp2(float x) {
#if __has_builtin(__builtin_amdgcn_exp2f)
    return __builtin_amdgcn_exp2f(x);     // bare v_exp_f32; scores bounded
#else
    return exp2f(x);
#endif
}
static __device__ __forceinline__ void swap32(int hi, unsigned a, unsigned b,
                                              unsigned& x, unsigned& y) {
#if __has_builtin(__builtin_amdgcn_permlane32_swap)
    typedef __attribute__((ext_vector_type(2))) int i32x2;
    i32x2 r = __builtin_amdgcn_permlane32_swap((int)a, (int)b, false, false);
    x = (unsigned)r[0]; y = (unsigned)r[1];
#else
    unsigned ta = (unsigned)__shfl_xor((int)a, 32);
    unsigned tb = (unsigned)__shfl_xor((int)b, 32);
    x = hi ? tb : a;
    y = hi ? b : ta;
#endif
}

// ---- LayerNorm row helper (one wave per 512-row) ---------------------------
static __device__ __forceinline__ void ln_row(
    const float* __restrict__ X, const float* __restrict__ gam,
    const float* __restrict__ bet, unsigned short* __restrict__ O,
    int row, int lane)
{
    const float4* xr = (const float4*)(X + (size_t)row * 512);
    float4 v0 = xr[lane * 2], v1 = xr[lane * 2 + 1];
    float vv[8] = {v0.x, v0.y, v0.z, v0.w, v1.x, v1.y, v1.z, v1.w};
    float s = 0.f, s2 = 0.f;
    #pragma unroll
    for (int j = 0; j < 8; ++j) { s += vv[j]; s2 += vv[j] * vv[j]; }
    #pragma unroll
    for (int d = 1; d < 64; d <<= 1) { s += __shfl_xor(s, d); s2 += __shfl_xor(s2, d); }
    float mean = s * (1.0f / 512.0f);
    float var  = s2 * (1.0f / 512.0f) - mean * mean;
    float rstd = rsqrtf(var + 1e-5f);
    int c = lane * 8;
    u16x8 o;
    #pragma unroll
    for (int j = 0; j < 8; ++j) o[j] = f2b((vv[j] - mean) * rstd * gam[c + j] + bet[c + j]);
    *(u16x8*)(O + (size_t)row * 512 + c) = o;
}

// ---- merged: weight prep (blocks 0..1023) + LN1 (blocks 1024..3071) -------
__global__ __launch_bounds__(256) void prep_ln_k(
    const float* __restrict__ Wq, const float* __restrict__ Wk, const float* __restrict__ Wv,
    const float* __restrict__ Wm, const float* __restrict__ Wo,
    unsigned short* __restrict__ wqT, unsigned short* __restrict__ wkT,
    unsigned short* __restrict__ wvT, unsigned short* __restrict__ wmT,
    unsigned short* __restrict__ woT,
    const float* __restrict__ X, const float* __restrict__ g1,
    const float* __restrict__ b1, unsigned short* __restrict__ h1)
{
    int bx = blockIdx.x;
    if (bx < 1024) {
        int idx = bx * 256 + threadIdx.x;     // idx = n*512 + k
        int n = idx >> 9, k = idx & 511;
        int h = n >> 6, e = n & 63;
        size_t src_qkv = ((size_t)h * 512 + k) * 64 + e;
        wqT[idx] = f2b(Wq[src_qkv]);
        wkT[idx] = f2b(Wk[src_qkv]);
        wvT[idx] = f2b(Wv[src_qkv]);
        wmT[idx] = f2b(Wm[(size_t)k * 512 + n]);
        woT[idx] = f2b(Wo[(size_t)k * 512 + n]);
    } else {
        int row = (bx - 1024) * 4 + (threadIdx.x >> 6);
        ln_row(X, g1, b1, h1, row, threadIdx.x & 63);
    }
}

// ---- LN, 4 rows per 256-thread block --------------------------------------
__global__ __launch_bounds__(256) void ln4_k(
    const float* __restrict__ X, const float* __restrict__ gam,
    const float* __restrict__ bet, unsigned short* __restrict__ O)
{
    int row = blockIdx.x * 4 + (threadIdx.x >> 6);
    ln_row(X, gam, bet, O, row, threadIdx.x & 63);
}

// ---- fused QKV GEMM: [8192,512] x Bt[1536,512]^T, DBUF glds16 pipeline ----
// T1: XCD-swizzled M-tile index — XCD k only touches A rows [k*1024,+1024).
__global__ __launch_bounds__(256) void gemm_qkv_k(
    const unsigned short* __restrict__ A, const unsigned short* __restrict__ Bt,
    const float* __restrict__ bq, const float* __restrict__ bk, const float* __restrict__ bv,
    unsigned short* __restrict__ Qo, unsigned short* __restrict__ Ko,
    unsigned short* __restrict__ VtO)
{
    __shared__ unsigned short Al[2][128 * 32];   // linear [row][k], row = 64B
    __shared__ unsigned short Bl[2][128 * 32];
    int tid = threadIdx.x;
    int wid = tid >> 6, lane = tid & 63;
    int lr = lane & 15, lg = lane >> 4;
    int bx = blockIdx.x;
    int xs = ((bx & 7) << 3) + (bx >> 3);        // bijective XCD swizzle (64 tiles)
    int m0 = xs * 128, n0 = blockIdx.y * 128;
    int seg = blockIdx.y >> 2;
    int wr = (wid >> 1) * 64, wc = (wid & 1) * 64;
    f32x4 acc[4][4] = {};
    const unsigned short* Ag = A  + (size_t)(m0 + wid * 32 + (lane >> 2)) * 512 + (lane & 3) * 8;
    const unsigned short* Bg = Bt + (size_t)(n0 + wid * 32 + (lane >> 2)) * 512 + (lane & 3) * 8;
    const int lofs = wid * 32 * 32;

    auto STAGE = [&](int buf, int k0) {
        glds16(Ag + k0,            Al[buf] + lofs);
        glds16(Ag + k0 + 16 * 512, Al[buf] + lofs + 16 * 32);
        glds16(Bg + k0,            Bl[buf] + lofs);
        glds16(Bg + k0 + 16 * 512, Bl[buf] + lofs + 16 * 32);
    };
    auto COMPUTE = [&](int buf) {
        bf16x8 af[4], bfr[4];
        #pragma unroll
        for (int m = 0; m < 4; ++m) af[m]  = *(const bf16x8*)(Al[buf] + (wr + m * 16 + lr) * 32 + lg * 8);
        #pragma unroll
        for (int n = 0; n < 4; ++n) bfr[n] = *(const bf16x8*)(Bl[buf] + (wc + n * 16 + lr) * 32 + lg * 8);
        #pragma unroll
        for (int m = 0; m < 4; ++m)
            #pragma unroll
            for (int n = 0; n < 4; ++n)
                acc[m][n] = __builtin_amdgcn_mfma_f32_16x16x32_bf16(af[m], bfr[n], acc[m][n], 0, 0, 0);
    };

    STAGE(0, 0);
    #pragma unroll 1
    for (int k0 = 0; k0 < 512; k0 += 64) {
        __syncthreads();
        if (k0 + 32 < 512) STAGE(1, k0 + 32);
        COMPUTE(0);
        __syncthreads();
        if (k0 + 64 < 512) STAGE(0, k0 + 64);
        COMPUTE(1);
    }

    const float* bb = seg == 0 ? bq : (seg == 1 ? bk : bv);
    unsigned short* dst = seg == 0 ? Qo : Ko;
    #pragma unroll
    for (int m = 0; m < 4; ++m)
      #pragma unroll
      for (int n = 0; n < 4; ++n) {
        int gr0 = m0 + wr + m * 16 + 4 * lg;
        int nc  = ((blockIdx.y & 3) << 7) + wc + n * 16 + lr;
        float bias = bb[nc];
        if (seg < 2) {
            #pragma unroll
            for (int j = 0; j < 4; ++j)
                dst[(size_t)(gr0 + j) * 512 + nc] = f2b(acc[m][n][j] + bias);
        } else {
            int bbk = gr0 >> 11, ss = gr0 & 2047, hh = nc >> 6, ee = nc & 63;
            ushort4 pv;
            pv.x = f2b(acc[m][n][0] + bias);
            pv.y = f2b(acc[m][n][1] + bias);
            pv.z = f2b(acc[m][n][2] + bias);
            pv.w = f2b(acc[m][n][3] + bias);
            *(ushort4*)&VtO[((size_t)((bbk * 8 + hh) * 64 + ee) << 11) + ss] = pv;
        }
      }
}

// ---- GEMM 128x64 tiles, DBUF glds16 pipeline, fp32 epilogue ---------------
template<int MODE>
__global__ __launch_bounds__(256) void gemm_n64_k(
    const unsigned short* __restrict__ A, const unsigned short* __restrict__ Bt,
    const float* __restrict__ bias, const float* __restrict__ aux,
    float* __restrict__ Cout)
{
    __shared__ unsigned short Al[2][128 * 32];
    __shared__ unsigned short Bl[2][64 * 32];
    int tid = threadIdx.x;
    int wid = tid >> 6, lane = tid & 63;
    int lr = lane & 15, lg = lane >> 4;
    int bx = blockIdx.x;
    int xs = ((bx & 7) << 3) + (bx >> 3);        // bijective XCD swizzle
    int m0 = xs * 128, n0 = blockIdx.y * 64;
    int wr = wid * 32;
    f32x4 acc[2][4] = {};
    const unsigned short* Ag = A  + (size_t)(m0 + wid * 32 + (lane >> 2)) * 512 + (lane & 3) * 8;
    const unsigned short* Bg = Bt + (size_t)(n0 + wid * 16 + (lane >> 2)) * 512 + (lane & 3) * 8;
    const int aofs = wid * 32 * 32;
    const int bofs = wid * 16 * 32;

    auto STAGE = [&](int buf, int k0) {
        glds16(Ag + k0,            Al[buf] + aofs);
        glds16(Ag + k0 + 16 * 512, Al[buf] + aofs + 16 * 32);
        glds16(Bg + k0,            Bl[buf] + bofs);
    };
    auto COMPUTE = [&](int buf) {
        bf16x8 af[2], bfr[4];
        #pragma unroll
        for (int m = 0; m < 2; ++m) af[m]  = *(const bf16x8*)(Al[buf] + (wr + m * 16 + lr) * 32 + lg * 8);
        #pragma unroll
        for (int n = 0; n < 4; ++n) bfr[n] = *(const bf16x8*)(Bl[buf] + (n * 16 + lr) * 32 + lg * 8);
        #pragma unroll
        for (int m = 0; m < 2; ++m)
            #pragma unroll
            for (int n = 0; n < 4; ++n)
                acc[m][n] = __builtin_amdgcn_mfma_f32_16x16x32_bf16(af[m], bfr[n], acc[m][n], 0, 0, 0);
    };

    STAGE(0, 0);
    #pragma unroll 1
    for (int k0 = 0; k0 < 512; k0 += 64) {
        __syncthreads();
        if (k0 + 32 < 512) STAGE(1, k0 + 32);
        COMPUTE(0);
        __syncthreads();
        if (k0 + 64 < 512) STAGE(0, k0 + 64);
        COMPUTE(1);
    }

    #pragma unroll
    for (int m = 0; m < 2; ++m)
      #pragma unroll
      for (int n = 0; n < 4; ++n)
        #pragma unroll
        for (int j = 0; j < 4; ++j) {
            int gr = m0 + wr + m * 16 + 4 * lg + j;
            int gc = n0 + n * 16 + lr;
            float v = acc[m][n][j] + bias[gc];
            if (MODE == 3) v = v > 0.0f ? v : 0.0f;
            Cout[(size_t)gr * 512 + gc] = v + aux[(size_t)gr * 512 + gc];
        }
}

// ---- attn12 (champion): glds16 pre-swizzled staging, dbuf, 1 barrier/tile -
// LDS content layout identical to attn7's swizzle:
//   token t, seg s(16B) lives at (t&31)*256 + (((t>>5)*128+s*16)^((t&15)<<4))
// Inversion for linear slot L=j*1024+l*16: row31=j*4+(l>>4), x=(l&15)^(row31&15)
//   -> t = 32*(x>>3)+row31, s = x&7
__global__ __launch_bounds__(128) void attn12_k(
    const unsigned short* __restrict__ Q, const unsigned short* __restrict__ K,
    const unsigned short* __restrict__ Vt, unsigned short* __restrict__ O)
{
    __shared__ __align__(16) unsigned short KlA[4096], KlB[4096];   // 8 KB each
    __shared__ __align__(16) unsigned short VlA[4096], VlB[4096];

    const int tid  = threadIdx.x;
    const int lane = tid & 63;
    const int q31  = lane & 31;
    const int hi   = lane >> 5;
    const int wid  = tid >> 6;           // 0: K-stager, 1: V-stager

    // XCD swizzle: 32 q-blocks of one (b,h) share an XCD's L2
    int bid = blockIdx.x;
    int xcd = bid & 7, idx = bid >> 3;   // idx 0..127
    int bh  = xcd + 8 * (idx >> 5);      // 0..31
    int qt  = idx & 31;
    int b = bh >> 3, h = bh & 7;
    int q0 = qt * 64 + wid * 32;

    const unsigned short* Qb = Q  + (size_t)b * 2048 * 512 + h * 64;
    const unsigned short* Kb = K  + (size_t)b * 2048 * 512 + h * 64;
    const unsigned short* Vb = Vt + (size_t)(b * 8 + h) * 64 * 2048;

    // Q B-frags, pre-scaled by 1/sqrt(dh) * log2(e)
    frag_u qf[4];
    const float qs = 0.125f * 1.44269504f;
    #pragma unroll
    for (int ds = 0; ds < 4; ++ds) {
        u16x8 raw = *(const u16x8*)(Qb + (size_t)(q0 + q31) * 512 + ds * 16 + hi * 8);
        #pragma unroll
        for (int i = 0; i < 4; ++i)
            qf[ds].u[i] = pack_bf16(b2f(raw[2 * i]) * qs, b2f(raw[2 * i + 1]) * qs);
    }

    // all-ones B-frag for the l-accumulating MFMA
    frag_u onesf;
    #pragma unroll
    for (int i = 0; i < 4; ++i) onesf.u[i] = 0x3F803F80u;

    // inverse-swizzle per-lane source offsets (ushort elements), j = 0..7
    unsigned soff[8];
    #pragma unroll
    for (int j = 0; j < 8; ++j) {
        int row31 = j * 4 + (lane >> 4);
        int x = (lane & 15) ^ (row31 & 15);
        int t = 32 * (x >> 3) + row31;
        int s = x & 7;
        soff[j] = (wid == 0) ? (unsigned)(t * 512 + s * 8)     // K[t][s*8..]
                             : (unsigned)(t * 2048 + s * 8);   // Vt row e=t
    }
    const unsigned short* Gb = (wid == 0) ? Kb : Vb;

    auto STAGE = [&](unsigned short* buf, int t0) {
        const unsigned short* g = Gb + (wid == 0 ? (size_t)t0 * 512 : (size_t)t0);
        #pragma unroll
        for (int j = 0; j < 8; ++j)
            glds16(g + soff[j], buf + j * 512);
    };

    f32x16 acc0, acc1, lacc;
    #pragma unroll
    for (int r = 0; r < 16; ++r) { acc0[r] = 0.0f; acc1[r] = 0.0f; lacc[r] = 0.0f; }
    const int swz = (q31 & 15) << 4;

    auto COMPUTE = [&](const unsigned short* Kh_, const unsigned short* Vh_) {
        const char* Kh = (const char*)Kh_;
        const char* Vh = (const char*)Vh_;
        f32x16 s0, s1;
        #pragma unroll
        for (int r = 0; r < 16; ++r) { s0[r] = 0.0f; s1[r] = 0.0f; }
        __builtin_amdgcn_s_setprio(1);
        #pragma unroll
        for (int ds = 0; ds < 4; ++ds) {
            bf16x8 k0 = *(const bf16x8*)(Kh + q31 * 256 + ((ds * 32 + hi * 16) ^ swz));
            bf16x8 k1 = *(const bf16x8*)(Kh + q31 * 256 + ((128 + ds * 32 + hi * 16) ^ swz));
            s0 = __builtin_amdgcn_mfma_f32_32x32x16_bf16(k0, qf[ds].v, s0, 0, 0, 0);
            s1 = __builtin_amdgcn_mfma_f32_32x32x16_bf16(k1, qf[ds].v, s1, 0, 0, 0);
        }
        __builtin_amdgcn_s_setprio(0);

        #pragma unroll
        for (int r = 0; r < 16; ++r) {
            s0[r] = fexp2(s0[r]);
            s1[r] = fexp2(s1[r]);
        }

        frag_u pa[4];
        #pragma unroll
        for (int g = 0; g < 2; ++g) {
            unsigned A0 = pack_bf16(s0[8 * g + 0], s0[8 * g + 1]);
            unsigned A1 = pack_bf16(s0[8 * g + 2], s0[8 * g + 3]);
            unsigned A2 = pack_bf16(s0[8 * g + 4], s0[8 * g + 5]);
            unsigned A3 = pack_bf16(s0[8 * g + 6], s0[8 * g + 7]);
            swap32(hi, A0, A2, pa[g].u[0], pa[g].u[2]);
            swap32(hi, A1, A3, pa[g].u[1], pa[g].u[3]);
            unsigned B0 = pack_bf16(s1[8 * g + 0], s1[8 * g + 1]);
            unsigned B1 = pack_bf16(s1[8 * g + 2], s1[8 * g + 3]);
            unsigned B2 = pack_bf16(s1[8 * g + 4], s1[8 * g + 5]);
            unsigned B3 = pack_bf16(s1[8 * g + 6], s1[8 * g + 7]);
            swap32(hi, B0, B2, pa[2 + g].u[0], pa[2 + g].u[2]);
            swap32(hi, B1, B3, pa[2 + g].u[1], pa[2 + g].u[3]);
        }

        __builtin_amdgcn_s_setprio(1);
        #pragma unroll
        for (int ks = 0; ks < 4; ++ks) {
            bf16x8 v0 = *(const bf16x8*)(Vh + q31 * 256 + ((ks * 32 + hi * 16) ^ swz));
            bf16x8 v1 = *(const bf16x8*)(Vh + q31 * 256 + ((128 + ks * 32 + hi * 16) ^ swz));
            acc0 = __builtin_amdgcn_mfma_f32_32x32x16_bf16(pa[ks].v, v0, acc0, 0, 0, 0);
            acc1 = __builtin_amdgcn_mfma_f32_32x32x16_bf16(pa[ks].v, v1, acc1, 0, 0, 0);
            lacc = __builtin_amdgcn_mfma_f32_32x32x16_bf16(pa[ks].v, onesf.v, lacc, 0, 0, 0);
        }
        __builtin_amdgcn_s_setprio(0);
    };

    // prologue: tile0 -> A
    STAGE(wid == 0 ? KlA : VlA, 0);
    __syncthreads();                       // drains glds (compiler vmcnt(0))

    #pragma unroll 1
    for (int it = 0; it < 32; it += 2) {
        if (it + 1 < 32) STAGE(wid == 0 ? KlB : VlB, (it + 1) * 64);
        COMPUTE(KlA, VlA);
        __syncthreads();
        if (it + 2 < 32) STAGE(wid == 0 ? KlA : VlA, (it + 2) * 64);
        COMPUTE(KlB, VlB);
        __syncthreads();
    }

    // epilogue: element-wise divide (lacc[r] holds rowsum for acc*'s row)
    #pragma unroll
    for (int r = 0; r < 16; ++r) {
        int cr = (r & 3) + 8 * (r >> 2) + 4 * hi;
        float li = 1.0f / lacc[r];
        size_t rowoff = (size_t)(b * 2048 + q0 + cr) * 512 + h * 64 + q31;
        O[rowoff]      = f2b(acc0[r] * li);
        O[rowoff + 32] = f2b(acc1[r] * li);
    }
}

// ---------------------------------------------------------------------------
extern "C" void kernel_launch(void* const* d_in, const int* in_sizes, int n_in,
                              void* d_out, int out_size, void* d_ws, size_t ws_size,
                              hipStream_t stream)
{
    const float* x  = (const float*)d_in[0];
    const float* g1 = (const float*)d_in[1];
    const float* b1 = (const float*)d_in[2];
    const float* Wq = (const float*)d_in[3];
    const float* bq = (const float*)d_in[4];
    const float* Wk = (const float*)d_in[5];
    const float* bk = (const float*)d_in[6];
    const float* Wv = (const float*)d_in[7];
    const float* bv = (const float*)d_in[8];
    const float* Wm = (const float*)d_in[9];
    const float* bm = (const float*)d_in[10];
    const float* g2 = (const float*)d_in[11];
    const float* b2 = (const float*)d_in[12];
    const float* Wo = (const float*)d_in[13];
    const float* bo = (const float*)d_in[14];
    float* out = (float*)d_out;

    char* ws = (char*)d_ws;
    const size_t EB = (size_t)8192 * 512 * 2;
    unsigned short* h1  = (unsigned short*)(ws);
    unsigned short* qb  = (unsigned short*)(ws + EB);
    unsigned short* kb  = (unsigned short*)(ws + 2 * EB);
    unsigned short* vtb = (unsigned short*)(ws + 3 * EB);
    unsigned short* ao  = (unsigned short*)(ws + 4 * EB);
    unsigned short* h2  = (unsigned short*)(ws + 5 * EB);
    float*          hlp = (float*)(ws + 6 * EB);
    unsigned short* wqT = (unsigned short*)(ws + 8 * EB);   // QKV stacked [1536][512]
    unsigned short* wkT = wqT + 512 * 512;
    unsigned short* wvT = wkT + 512 * 512;
    unsigned short* wmT = wvT + 512 * 512;
    unsigned short* woT = wmT + 512 * 512;

    prep_ln_k<<<3072, 256, 0, stream>>>(Wq, Wk, Wv, Wm, Wo,
                                        wqT, wkT, wvT, wmT, woT,
                                        x, g1, b1, h1);
    gemm_qkv_k<<<dim3(64, 12), 256, 0, stream>>>(h1, wqT, bq, bk, bv, qb, kb, vtb);
    attn12_k<<<1024, 128, 0, stream>>>(qb, kb, vtb, ao);
    gemm_n64_k<2><<<dim3(64, 8), 256, 0, stream>>>(ao, wmT, bm, x, hlp);
    ln4_k<<<2048, 256, 0, stream>>>(hlp, g2, b2, h2);
    gemm_n64_k<3><<<dim3(64, 8), 256, 0, stream>>>(h2, woT, bo, hlp, out);
}

// Round 18
// 127.375 us; speedup vs baseline: 1.0993x; 1.0244x over previous
//
#include <hip/hip_runtime.h>
#include <hip/hip_bf16.h>

// ---------------------------------------------------------------------------
// TrXL block on MI355X. bf16 MFMA everywhere, bf16 residual spine (R18).
//   h1, Q, K, attn_out, h2 : bf16 [B*S=8192, 512]
//   Vt                     : bf16 [B, H, dh=64, S=2048]
//   hlp (h_ln_post)        : bf16 [8192, 512]   (was fp32 — 24 MB traffic cut)
//   weights prepped to Bt  : bf16 [N][K=512]  (QKV stacked to N=1536)
// attn12_k (champion): 2-wave, glds16 pre-swizzled staging, dbuf,
//   1 barrier/tile, max-free softmax, lacc via ones-MFMA.
// GEMMs: m97 double-buffered glds16 pipeline.
// prep_ln_k merges weight-prep + LN1; LNs 4 rows/block.
// ---------------------------------------------------------------------------

typedef __attribute__((ext_vector_type(8))) short bf16x8;
typedef __attribute__((ext_vector_type(4))) float f32x4;
typedef __attribute__((ext_vector_type(16))) float f32x16;
typedef __attribute__((ext_vector_type(8))) unsigned short u16x8;

typedef union { bf16x8 v; unsigned u[4]; u16x8 s; } frag_u;

typedef const unsigned int __attribute__((address_space(1)))* gas_t;
typedef unsigned int __attribute__((address_space(3)))* las_t;
static __device__ __forceinline__ void glds16(const void* g, void* l) {
    __builtin_amdgcn_global_load_lds((gas_t)g, (las_t)l, 16, 0, 0);
}

static __device__ __forceinline__ unsigned short f2b(float f) {
    union { float f; unsigned u; } a; a.f = f;
    unsigned r = a.u + 0x7FFFu + ((a.u >> 16) & 1u);   // RNE
    return (unsigned short)(r >> 16);
}
static __device__ __forceinline__ float b2f(unsigned short u) {
    union { unsigned u; float f; } c; c.u = ((unsigned)u) << 16; return c.f;
}
static __device__ __forceinline__ unsigned pack_bf16(float lo, float hi) {
    __hip_bfloat162 p = __float22bfloat162_rn(make_float2(lo, hi));
    unsigned r; __builtin_memcpy(&r, &p, 4); return r;
}
static __device__ __forceinline__ float fexp2(float x) {
#if __has_builtin(__builtin_amdgcn_exp2f)
    return __builtin_amdgcn_exp2f(x);     // bare v_exp_f32; scores bounded
#else
    return exp2f(x);
#endif
}
static __device__ __forceinline__ void swap32(int hi, unsigned a, unsigned b,
                                              unsigned& x, unsigned& y) {
#if __has_builtin(__builtin_amdgcn_permlane32_swap)
    typedef __attribute__((ext_vector_type(2))) int i32x2;
    i32x2 r = __builtin_amdgcn_permlane32_swap((int)a, (int)b, false, false);
    x = (unsigned)r[0]; y = (unsigned)r[1];
#else
    unsigned ta = (unsigned)__shfl_xor((int)a, 32);
    unsigned tb = (unsigned)__shfl_xor((int)b, 32);
    x = hi ? tb : a;
    y = hi ? b : ta;
#endif
}

// ---- LayerNorm row helpers (one wave per 512-row) --------------------------
static __device__ __forceinline__ void ln_row_f32(
    const float* __restrict__ X, const float* __restrict__ gam,
    const float* __restrict__ bet, unsigned short* __restrict__ O,
    int row, int lane)
{
    const float4* xr = (const float4*)(X + (size_t)row * 512);
    float4 v0 = xr[lane * 2], v1 = xr[lane * 2 + 1];
    float vv[8] = {v0.x, v0.y, v0.z, v0.w, v1.x, v1.y, v1.z, v1.w};
    float s = 0.f, s2 = 0.f;
    #pragma unroll
    for (int j = 0; j < 8; ++j) { s += vv[j]; s2 += vv[j] * vv[j]; }
    #pragma unroll
    for (int d = 1; d < 64; d <<= 1) { s += __shfl_xor(s, d); s2 += __shfl_xor(s2, d); }
    float mean = s * (1.0f / 512.0f);
    float var  = s2 * (1.0f / 512.0f) - mean * mean;
    float rstd = rsqrtf(var + 1e-5f);
    int c = lane * 8;
    u16x8 o;
    #pragma unroll
    for (int j = 0; j < 8; ++j) o[j] = f2b((vv[j] - mean) * rstd * gam[c + j] + bet[c + j]);
    *(u16x8*)(O + (size_t)row * 512 + c) = o;
}

static __device__ __forceinline__ void ln_row_bf16(
    const unsigned short* __restrict__ X, const float* __restrict__ gam,
    const float* __restrict__ bet, unsigned short* __restrict__ O,
    int row, int lane)
{
    u16x8 raw = *(const u16x8*)(X + (size_t)row * 512 + lane * 8);
    float vv[8];
    #pragma unroll
    for (int j = 0; j < 8; ++j) vv[j] = b2f(raw[j]);
    float s = 0.f, s2 = 0.f;
    #pragma unroll
    for (int j = 0; j < 8; ++j) { s += vv[j]; s2 += vv[j] * vv[j]; }
    #pragma unroll
    for (int d = 1; d < 64; d <<= 1) { s += __shfl_xor(s, d); s2 += __shfl_xor(s2, d); }
    float mean = s * (1.0f / 512.0f);
    float var  = s2 * (1.0f / 512.0f) - mean * mean;
    float rstd = rsqrtf(var + 1e-5f);
    int c = lane * 8;
    u16x8 o;
    #pragma unroll
    for (int j = 0; j < 8; ++j) o[j] = f2b((vv[j] - mean) * rstd * gam[c + j] + bet[c + j]);
    *(u16x8*)(O + (size_t)row * 512 + c) = o;
}

// ---- merged: weight prep (blocks 0..1023) + LN1 (blocks 1024..3071) -------
__global__ __launch_bounds__(256) void prep_ln_k(
    const float* __restrict__ Wq, const float* __restrict__ Wk, const float* __restrict__ Wv,
    const float* __restrict__ Wm, const float* __restrict__ Wo,
    unsigned short* __restrict__ wqT, unsigned short* __restrict__ wkT,
    unsigned short* __restrict__ wvT, unsigned short* __restrict__ wmT,
    unsigned short* __restrict__ woT,
    const float* __restrict__ X, const float* __restrict__ g1,
    const float* __restrict__ b1, unsigned short* __restrict__ h1)
{
    int bx = blockIdx.x;
    if (bx < 1024) {
        int idx = bx * 256 + threadIdx.x;     // idx = n*512 + k
        int n = idx >> 9, k = idx & 511;
        int h = n >> 6, e = n & 63;
        size_t src_qkv = ((size_t)h * 512 + k) * 64 + e;
        wqT[idx] = f2b(Wq[src_qkv]);
        wkT[idx] = f2b(Wk[src_qkv]);
        wvT[idx] = f2b(Wv[src_qkv]);
        wmT[idx] = f2b(Wm[(size_t)k * 512 + n]);
        woT[idx] = f2b(Wo[(size_t)k * 512 + n]);
    } else {
        int row = (bx - 1024) * 4 + (threadIdx.x >> 6);
        ln_row_f32(X, g1, b1, h1, row, threadIdx.x & 63);
    }
}

// ---- LN2: bf16 input, 4 rows per 256-thread block --------------------------
__global__ __launch_bounds__(256) void ln4b_k(
    const unsigned short* __restrict__ X, const float* __restrict__ gam,
    const float* __restrict__ bet, unsigned short* __restrict__ O)
{
    int row = blockIdx.x * 4 + (threadIdx.x >> 6);
    ln_row_bf16(X, gam, bet, O, row, threadIdx.x & 63);
}

// ---- fused QKV GEMM: [8192,512] x Bt[1536,512]^T, DBUF glds16 pipeline ----
__global__ __launch_bounds__(256) void gemm_qkv_k(
    const unsigned short* __restrict__ A, const unsigned short* __restrict__ Bt,
    const float* __restrict__ bq, const float* __restrict__ bk, const float* __restrict__ bv,
    unsigned short* __restrict__ Qo, unsigned short* __restrict__ Ko,
    unsigned short* __restrict__ VtO)
{
    __shared__ unsigned short Al[2][128 * 32];   // linear [row][k], row = 64B
    __shared__ unsigned short Bl[2][128 * 32];
    int tid = threadIdx.x;
    int wid = tid >> 6, lane = tid & 63;
    int lr = lane & 15, lg = lane >> 4;
    int m0 = blockIdx.x * 128, n0 = blockIdx.y * 128;
    int seg = blockIdx.y >> 2;
    int wr = (wid >> 1) * 64, wc = (wid & 1) * 64;
    f32x4 acc[4][4] = {};
    const unsigned short* Ag = A  + (size_t)(m0 + wid * 32 + (lane >> 2)) * 512 + (lane & 3) * 8;
    const unsigned short* Bg = Bt + (size_t)(n0 + wid * 32 + (lane >> 2)) * 512 + (lane & 3) * 8;
    const int lofs = wid * 32 * 32;

    auto STAGE = [&](int buf, int k0) {
        glds16(Ag + k0,            Al[buf] + lofs);
        glds16(Ag + k0 + 16 * 512, Al[buf] + lofs + 16 * 32);
        glds16(Bg + k0,            Bl[buf] + lofs);
        glds16(Bg + k0 + 16 * 512, Bl[buf] + lofs + 16 * 32);
    };
    auto COMPUTE = [&](int buf) {
        bf16x8 af[4], bfr[4];
        #pragma unroll
        for (int m = 0; m < 4; ++m) af[m]  = *(const bf16x8*)(Al[buf] + (wr + m * 16 + lr) * 32 + lg * 8);
        #pragma unroll
        for (int n = 0; n < 4; ++n) bfr[n] = *(const bf16x8*)(Bl[buf] + (wc + n * 16 + lr) * 32 + lg * 8);
        #pragma unroll
        for (int m = 0; m < 4; ++m)
            #pragma unroll
            for (int n = 0; n < 4; ++n)
                acc[m][n] = __builtin_amdgcn_mfma_f32_16x16x32_bf16(af[m], bfr[n], acc[m][n], 0, 0, 0);
    };

    STAGE(0, 0);
    #pragma unroll 1
    for (int k0 = 0; k0 < 512; k0 += 64) {
        __syncthreads();
        if (k0 + 32 < 512) STAGE(1, k0 + 32);
        COMPUTE(0);
        __syncthreads();
        if (k0 + 64 < 512) STAGE(0, k0 + 64);
        COMPUTE(1);
    }

    const float* bb = seg == 0 ? bq : (seg == 1 ? bk : bv);
    unsigned short* dst = seg == 0 ? Qo : Ko;
    #pragma unroll
    for (int m = 0; m < 4; ++m)
      #pragma unroll
      for (int n = 0; n < 4; ++n) {
        int gr0 = m0 + wr + m * 16 + 4 * lg;
        int nc  = ((blockIdx.y & 3) << 7) + wc + n * 16 + lr;
        float bias = bb[nc];
        if (seg < 2) {
            #pragma unroll
            for (int j = 0; j < 4; ++j)
                dst[(size_t)(gr0 + j) * 512 + nc] = f2b(acc[m][n][j] + bias);
        } else {
            int bbk = gr0 >> 11, ss = gr0 & 2047, hh = nc >> 6, ee = nc & 63;
            ushort4 pv;
            pv.x = f2b(acc[m][n][0] + bias);
            pv.y = f2b(acc[m][n][1] + bias);
            pv.z = f2b(acc[m][n][2] + bias);
            pv.w = f2b(acc[m][n][3] + bias);
            *(ushort4*)&VtO[((size_t)((bbk * 8 + hh) * 64 + ee) << 11) + ss] = pv;
        }
      }
}

// ---- GEMM 128x64 tiles, DBUF glds16 pipeline ------------------------------
// MODE 2: hlp_bf16 = bf16(acc + bias + auxf[fp32 x])     (Wm proj + residual)
// MODE 3: out_f32  = relu(acc + bias) + b2f(auxb[hlp])   (Wo FC + residual)
template<int MODE>
__global__ __launch_bounds__(256) void gemm_n64_k(
    const unsigned short* __restrict__ A, const unsigned short* __restrict__ Bt,
    const float* __restrict__ bias, const float* __restrict__ auxf,
    const unsigned short* __restrict__ auxb, void* __restrict__ Cout)
{
    __shared__ unsigned short Al[2][128 * 32];
    __shared__ unsigned short Bl[2][64 * 32];
    int tid = threadIdx.x;
    int wid = tid >> 6, lane = tid & 63;
    int lr = lane & 15, lg = lane >> 4;
    int m0 = blockIdx.x * 128, n0 = blockIdx.y * 64;
    int wr = wid * 32;
    f32x4 acc[2][4] = {};
    const unsigned short* Ag = A  + (size_t)(m0 + wid * 32 + (lane >> 2)) * 512 + (lane & 3) * 8;
    const unsigned short* Bg = Bt + (size_t)(n0 + wid * 16 + (lane >> 2)) * 512 + (lane & 3) * 8;
    const int aofs = wid * 32 * 32;
    const int bofs = wid * 16 * 32;

    auto STAGE = [&](int buf, int k0) {
        glds16(Ag + k0,            Al[buf] + aofs);
        glds16(Ag + k0 + 16 * 512, Al[buf] + aofs + 16 * 32);
        glds16(Bg + k0,            Bl[buf] + bofs);
    };
    auto COMPUTE = [&](int buf) {
        bf16x8 af[2], bfr[4];
        #pragma unroll
        for (int m = 0; m < 2; ++m) af[m]  = *(const bf16x8*)(Al[buf] + (wr + m * 16 + lr) * 32 + lg * 8);
        #pragma unroll
        for (int n = 0; n < 4; ++n) bfr[n] = *(const bf16x8*)(Bl[buf] + (n * 16 + lr) * 32 + lg * 8);
        #pragma unroll
        for (int m = 0; m < 2; ++m)
            #pragma unroll
            for (int n = 0; n < 4; ++n)
                acc[m][n] = __builtin_amdgcn_mfma_f32_16x16x32_bf16(af[m], bfr[n], acc[m][n], 0, 0, 0);
    };

    STAGE(0, 0);
    #pragma unroll 1
    for (int k0 = 0; k0 < 512; k0 += 64) {
        __syncthreads();
        if (k0 + 32 < 512) STAGE(1, k0 + 32);
        COMPUTE(0);
        __syncthreads();
        if (k0 + 64 < 512) STAGE(0, k0 + 64);
        COMPUTE(1);
    }

    #pragma unroll
    for (int m = 0; m < 2; ++m)
      #pragma unroll
      for (int n = 0; n < 4; ++n)
        #pragma unroll
        for (int j = 0; j < 4; ++j) {
            int gr = m0 + wr + m * 16 + 4 * lg + j;
            int gc = n0 + n * 16 + lr;
            float v = acc[m][n][j] + bias[gc];
            size_t off = (size_t)gr * 512 + gc;
            if (MODE == 2) {
                ((unsigned short*)Cout)[off] = f2b(v + auxf[off]);
            } else {
                float r = v > 0.0f ? v : 0.0f;
                ((float*)Cout)[off] = r + b2f(auxb[off]);
            }
        }
}

// ---- attn12 (champion): glds16 pre-swizzled staging, dbuf, 1 barrier/tile -
// LDS content layout identical to attn7's swizzle:
//   token t, seg s(16B) lives at (t&31)*256 + (((t>>5)*128+s*16)^((t&15)<<4))
// Inversion for linear slot L=j*1024+l*16: row31=j*4+(l>>4), x=(l&15)^(row31&15)
//   -> t = 32*(x>>3)+row31, s = x&7
__global__ __launch_bounds__(128) void attn12_k(
    const unsigned short* __restrict__ Q, const unsigned short* __restrict__ K,
    const unsigned short* __restrict__ Vt, unsigned short* __restrict__ O)
{
    __shared__ __align__(16) unsigned short KlA[4096], KlB[4096];   // 8 KB each
    __shared__ __align__(16) unsigned short VlA[4096], VlB[4096];

    const int tid  = threadIdx.x;
    const int lane = tid & 63;
    const int q31  = lane & 31;
    const int hi   = lane >> 5;
    const int wid  = tid >> 6;           // 0: K-stager, 1: V-stager

    // XCD swizzle: 32 q-blocks of one (b,h) share an XCD's L2
    int bid = blockIdx.x;
    int xcd = bid & 7, idx = bid >> 3;   // idx 0..127
    int bh  = xcd + 8 * (idx >> 5);      // 0..31
    int qt  = idx & 31;
    int b = bh >> 3, h = bh & 7;
    int q0 = qt * 64 + wid * 32;

    const unsigned short* Qb = Q  + (size_t)b * 2048 * 512 + h * 64;
    const unsigned short* Kb = K  + (size_t)b * 2048 * 512 + h * 64;
    const unsigned short* Vb = Vt + (size_t)(b * 8 + h) * 64 * 2048;

    // Q B-frags, pre-scaled by 1/sqrt(dh) * log2(e)
    frag_u qf[4];
    const float qs = 0.125f * 1.44269504f;
    #pragma unroll
    for (int ds = 0; ds < 4; ++ds) {
        u16x8 raw = *(const u16x8*)(Qb + (size_t)(q0 + q31) * 512 + ds * 16 + hi * 8);
        #pragma unroll
        for (int i = 0; i < 4; ++i)
            qf[ds].u[i] = pack_bf16(b2f(raw[2 * i]) * qs, b2f(raw[2 * i + 1]) * qs);
    }

    // all-ones B-frag for the l-accumulating MFMA
    frag_u onesf;
    #pragma unroll
    for (int i = 0; i < 4; ++i) onesf.u[i] = 0x3F803F80u;

    // inverse-swizzle per-lane source offsets (ushort elements), j = 0..7
    unsigned soff[8];
    #pragma unroll
    for (int j = 0; j < 8; ++j) {
        int row31 = j * 4 + (lane >> 4);
        int x = (lane & 15) ^ (row31 & 15);
        int t = 32 * (x >> 3) + row31;
        int s = x & 7;
        soff[j] = (wid == 0) ? (unsigned)(t * 512 + s * 8)     // K[t][s*8..]
                             : (unsigned)(t * 2048 + s * 8);   // Vt row e=t
    }
    const unsigned short* Gb = (wid == 0) ? Kb : Vb;

    auto STAGE = [&](unsigned short* buf, int t0) {
        const unsigned short* g = Gb + (wid == 0 ? (size_t)t0 * 512 : (size_t)t0);
        #pragma unroll
        for (int j = 0; j < 8; ++j)
            glds16(g + soff[j], buf + j * 512);
    };

    f32x16 acc0, acc1, lacc;
    #pragma unroll
    for (int r = 0; r < 16; ++r) { acc0[r] = 0.0f; acc1[r] = 0.0f; lacc[r] = 0.0f; }
    const int swz = (q31 & 15) << 4;

    auto COMPUTE = [&](const unsigned short* Kh_, const unsigned short* Vh_) {
        const char* Kh = (const char*)Kh_;
        const char* Vh = (const char*)Vh_;
        f32x16 s0, s1;
        #pragma unroll
        for (int r = 0; r < 16; ++r) { s0[r] = 0.0f; s1[r] = 0.0f; }
        __builtin_amdgcn_s_setprio(1);
        #pragma unroll
        for (int ds = 0; ds < 4; ++ds) {
            bf16x8 k0 = *(const bf16x8*)(Kh + q31 * 256 + ((ds * 32 + hi * 16) ^ swz));
            bf16x8 k1 = *(const bf16x8*)(Kh + q31 * 256 + ((128 + ds * 32 + hi * 16) ^ swz));
            s0 = __builtin_amdgcn_mfma_f32_32x32x16_bf16(k0, qf[ds].v, s0, 0, 0, 0);
            s1 = __builtin_amdgcn_mfma_f32_32x32x16_bf16(k1, qf[ds].v, s1, 0, 0, 0);
        }
        __builtin_amdgcn_s_setprio(0);

        #pragma unroll
        for (int r = 0; r < 16; ++r) {
            s0[r] = fexp2(s0[r]);
            s1[r] = fexp2(s1[r]);
        }

        frag_u pa[4];
        #pragma unroll
        for (int g = 0; g < 2; ++g) {
            unsigned A0 = pack_bf16(s0[8 * g + 0], s0[8 * g + 1]);
            unsigned A1 = pack_bf16(s0[8 * g + 2], s0[8 * g + 3]);
            unsigned A2 = pack_bf16(s0[8 * g + 4], s0[8 * g + 5]);
            unsigned A3 = pack_bf16(s0[8 * g + 6], s0[8 * g + 7]);
            swap32(hi, A0, A2, pa[g].u[0], pa[g].u[2]);
            swap32(hi, A1, A3, pa[g].u[1], pa[g].u[3]);
            unsigned B0 = pack_bf16(s1[8 * g + 0], s1[8 * g + 1]);
            unsigned B1 = pack_bf16(s1[8 * g + 2], s1[8 * g + 3]);
            unsigned B2 = pack_bf16(s1[8 * g + 4], s1[8 * g + 5]);
            unsigned B3 = pack_bf16(s1[8 * g + 6], s1[8 * g + 7]);
            swap32(hi, B0, B2, pa[2 + g].u[0], pa[2 + g].u[2]);
            swap32(hi, B1, B3, pa[2 + g].u[1], pa[2 + g].u[3]);
        }

        __builtin_amdgcn_s_setprio(1);
        #pragma unroll
        for (int ks = 0; ks < 4; ++ks) {
            bf16x8 v0 = *(const bf16x8*)(Vh + q31 * 256 + ((ks * 32 + hi * 16) ^ swz));
            bf16x8 v1 = *(const bf16x8*)(Vh + q31 * 256 + ((128 + ks * 32 + hi * 16) ^ swz));
            acc0 = __builtin_amdgcn_mfma_f32_32x32x16_bf16(pa[ks].v, v0, acc0, 0, 0, 0);
            acc1 = __builtin_amdgcn_mfma_f32_32x32x16_bf16(pa[ks].v, v1, acc1, 0, 0, 0);
            lacc = __builtin_amdgcn_mfma_f32_32x32x16_bf16(pa[ks].v, onesf.v, lacc, 0, 0, 0);
        }
        __builtin_amdgcn_s_setprio(0);
    };

    // prologue: tile0 -> A
    STAGE(wid == 0 ? KlA : VlA, 0);
    __syncthreads();                       // drains glds (compiler vmcnt(0))

    #pragma unroll 1
    for (int it = 0; it < 32; it += 2) {
        if (it + 1 < 32) STAGE(wid == 0 ? KlB : VlB, (it + 1) * 64);
        COMPUTE(KlA, VlA);
        __syncthreads();
        if (it + 2 < 32) STAGE(wid == 0 ? KlA : VlA, (it + 2) * 64);
        COMPUTE(KlB, VlB);
        __syncthreads();
    }

    // epilogue: element-wise divide (lacc[r] holds rowsum for acc*'s row)
    #pragma unroll
    for (int r = 0; r < 16; ++r) {
        int cr = (r & 3) + 8 * (r >> 2) + 4 * hi;
        float li = 1.0f / lacc[r];
        size_t rowoff = (size_t)(b * 2048 + q0 + cr) * 512 + h * 64 + q31;
        O[rowoff]      = f2b(acc0[r] * li);
        O[rowoff + 32] = f2b(acc1[r] * li);
    }
}

// ---------------------------------------------------------------------------
extern "C" void kernel_launch(void* const* d_in, const int* in_sizes, int n_in,
                              void* d_out, int out_size, void* d_ws, size_t ws_size,
                              hipStream_t stream)
{
    const float* x  = (const float*)d_in[0];
    const float* g1 = (const float*)d_in[1];
    const float* b1 = (const float*)d_in[2];
    const float* Wq = (const float*)d_in[3];
    const float* bq = (const float*)d_in[4];
    const float* Wk = (const float*)d_in[5];
    const float* bk = (const float*)d_in[6];
    const float* Wv = (const float*)d_in[7];
    const float* bv = (const float*)d_in[8];
    const float* Wm = (const float*)d_in[9];
    const float* bm = (const float*)d_in[10];
    const float* g2 = (const float*)d_in[11];
    const float* b2 = (const float*)d_in[12];
    const float* Wo = (const float*)d_in[13];
    const float* bo = (const float*)d_in[14];
    float* out = (float*)d_out;

    char* ws = (char*)d_ws;
    const size_t EB = (size_t)8192 * 512 * 2;
    unsigned short* h1  = (unsigned short*)(ws);
    unsigned short* qb  = (unsigned short*)(ws + EB);
    unsigned short* kb  = (unsigned short*)(ws + 2 * EB);
    unsigned short* vtb = (unsigned short*)(ws + 3 * EB);
    unsigned short* ao  = (unsigned short*)(ws + 4 * EB);
    unsigned short* h2  = (unsigned short*)(ws + 5 * EB);
    unsigned short* hlp = (unsigned short*)(ws + 6 * EB);   // bf16 residual spine
    unsigned short* wqT = (unsigned short*)(ws + 8 * EB);   // QKV stacked [1536][512]
    unsigned short* wkT = wqT + 512 * 512;
    unsigned short* wvT = wkT + 512 * 512;
    unsigned short* wmT = wvT + 512 * 512;
    unsigned short* woT = wmT + 512 * 512;

    prep_ln_k<<<3072, 256, 0, stream>>>(Wq, Wk, Wv, Wm, Wo,
                                        wqT, wkT, wvT, wmT, woT,
                                        x, g1, b1, h1);
    gemm_qkv_k<<<dim3(64, 12), 256, 0, stream>>>(h1, wqT, bq, bk, bv, qb, kb, vtb);
    attn12_k<<<1024, 128, 0, stream>>>(qb, kb, vtb, ao);
    gemm_n64_k<2><<<dim3(64, 8), 256, 0, stream>>>(ao, wmT, bm, x, nullptr, hlp);
    ln4b_k<<<2048, 256, 0, stream>>>(hlp, g2, b2, h2);
    gemm_n64_k<3><<<dim3(64, 8), 256, 0, stream>>>(h2, woT, bo, nullptr, hlp, out);
}